// Round 7
// baseline (428.489 us; speedup 1.0000x reference)
//
#include <hip/hip_runtime.h>
#include <stdint.h>

#define B_ 4
#define N_ 2048
#define C_ 1024
#define H_ 16
#define D_ 64
#define M_ (B_*N_)      // 8192 rows
#define N3_ (3*C_)      // 3072

typedef __attribute__((ext_vector_type(8))) __bf16 bf16x8;
typedef bf16x8 bf16x8_ma __attribute__((may_alias));
typedef __attribute__((ext_vector_type(4))) float floatx4;
typedef __attribute__((ext_vector_type(2))) unsigned int u32x2;
typedef u32x2 u32x2_ma __attribute__((may_alias));
typedef unsigned short u16;
typedef unsigned int u32;

typedef __attribute__((address_space(1))) const void void_g;
typedef __attribute__((address_space(3))) void void_l;

__device__ __forceinline__ void glds16(const void* g, void* l) {
  __builtin_amdgcn_global_load_lds((void_g*)g, (void_l*)l, 16, 0, 0);
}

__device__ __forceinline__ u16 f2bf(float f) {
  union { float f; u32 u; } x; x.f = f;
  u32 r = x.u + 0x7fffu + ((x.u >> 16) & 1u);   // RNE
  return (u16)(r >> 16);
}

__device__ __forceinline__ float fexp2(float x) {
#if __has_builtin(__builtin_amdgcn_exp2f)
  return __builtin_amdgcn_exp2f(x);
#else
  return exp2f(x);
#endif
}

// ---------------- x fp32 -> bf16, flat ------------------------------------
__global__ __launch_bounds__(256)
void convert_x(const float4* __restrict__ in, uint2* __restrict__ out, int n4) {
  int idx = blockIdx.x * 256 + threadIdx.x;
  if (idx >= n4) return;
  float4 v = in[idx];
  union { u16 a[4]; uint2 u; } p;
  p.a[0] = f2bf(v.x); p.a[1] = f2bf(v.y); p.a[2] = f2bf(v.z); p.a[3] = f2bf(v.w);
  out[idx] = p.u;
}

// -------- fp32 in[R][Ccols] -> bf16 out[Ccols][R] (transpose+convert) -----
__global__ __launch_bounds__(256)
void transpose_cvt(const float* __restrict__ in, u16* __restrict__ out,
                   int R, int Ccols) {
  __shared__ u16 tile[64][65];
  int c0 = blockIdx.x * 64, r0 = blockIdx.y * 64;
  int tid = threadIdx.x;
#pragma unroll
  for (int it = 0; it < 16; ++it) {
    int idx = it * 256 + tid;
    int r = idx >> 6, c = idx & 63;
    tile[c][r] = f2bf(in[(size_t)(r0 + r) * Ccols + c0 + c]);
  }
  __syncthreads();
#pragma unroll
  for (int it = 0; it < 16; ++it) {
    int idx = it * 256 + tid;
    int oc = idx >> 6, orr = idx & 63;
    out[(size_t)(c0 + oc) * R + r0 + orr] = tile[oc][orr];
  }
}

// -------- V section of qkv(bf16) -> Vt[bh][d][n], key-PERMUTED ------------
// Within each 64-key tile, position c holds actual key pi(c)=(c&3)*16+(c>>2).
__global__ __launch_bounds__(256)
void transpose_v(const u16* __restrict__ qkv, u16* __restrict__ vt) {
  __shared__ u16 tile[64][65];
  int bh = blockIdx.y, b = bh >> 4, h = bh & 15;
  int n0 = blockIdx.x * 64;
  int tid = threadIdx.x;
#pragma unroll
  for (int it = 0; it < 16; ++it) {
    int idx = it * 256 + tid;
    int n = idx >> 6, d = idx & 63;
    tile[d][n] = qkv[(size_t)(b * N_ + n0 + n) * N3_ + 2 * C_ + h * D_ + d];
  }
  __syncthreads();
#pragma unroll
  for (int it = 0; it < 16; ++it) {
    int idx = it * 256 + tid;
    int d = idx >> 6, n = idx & 63;          // n = actual key within tile
    int np = ((n & 15) << 2) | (n >> 4);     // pi^-1(n): position in vt
    vt[(size_t)(bh * D_ + d) * N_ + n0 + np] = tile[d][n];
  }
}

// ------- C = A[M,*lda](bf16) * Bt[N,K]^T(bf16) + bias(f32), opt RMSNorm ---
// SMALL-TILE config: 64x128 block, 4 waves of 32x64, BK=32.
// acc 2x4 (32 VGPR), 6 ds_read_b128 : 8 MFMA, 12 KB LDS -> ~5 blocks/CU;
// barrier drains decorrelate across independent blocks per CU.
__global__ __launch_bounds__(256, 5)
void gemm_bt(const u16* __restrict__ A, const u16* __restrict__ Bt,
             const float* __restrict__ bias, void* __restrict__ Cout,
             int Ncols, int lda, int do_rms, int out_fp32,
             const float* __restrict__ qn, const float* __restrict__ kn) {
  __shared__ __align__(16) u16 sA[4 * 512];   // 64 rows  = 4 frag-blocks
  __shared__ __align__(16) u16 sB[8 * 512];   // 128 rows = 8 frag-blocks
  const int K = C_;
  int tid = threadIdx.x;
  int wave = tid >> 6, lane = tid & 63;
  int lrow = lane & 15, lq = lane >> 4;
  int n0 = blockIdx.x * 128;
  int m0 = blockIdx.y * 64;
  int wm = wave >> 1, wn = wave & 1;

  floatx4 acc[2][4];
#pragma unroll
  for (int i = 0; i < 2; ++i)
#pragma unroll
    for (int j = 0; j < 4; ++j) acc[i][j] = (floatx4){0.f, 0.f, 0.f, 0.f};

  const u16* ga  = A  + (size_t)(m0 + wave * 16 + lrow) * lda + lq * 8;
  const u16* gb0 = Bt + (size_t)(n0 + (2 * wave + 0) * 16 + lrow) * K + lq * 8;
  const u16* gb1 = Bt + (size_t)(n0 + (2 * wave + 1) * 16 + lrow) * K + lq * 8;
  u16* la  = sA + wave * 512;
  u16* lb0 = sB + (2 * wave + 0) * 512;
  u16* lb1 = sB + (2 * wave + 1) * 512;

  for (int kt = 0; kt < K; kt += 32) {
    glds16(ga + kt,  la);
    glds16(gb0 + kt, lb0);
    glds16(gb1 + kt, lb1);
    __syncthreads();
    bf16x8 af[2], bfr[4];
#pragma unroll
    for (int i = 0; i < 2; ++i)
      af[i] = *(const bf16x8_ma*)(sA + (wm * 2 + i) * 512 + lane * 8);
#pragma unroll
    for (int j = 0; j < 4; ++j)
      bfr[j] = *(const bf16x8_ma*)(sB + (wn * 4 + j) * 512 + lane * 8);
#pragma unroll
    for (int i = 0; i < 2; ++i)
#pragma unroll
      for (int j = 0; j < 4; ++j)
        acc[i][j] = __builtin_amdgcn_mfma_f32_16x16x32_bf16(af[i], bfr[j], acc[i][j], 0, 0, 0);
    __syncthreads();
  }

  int colbase = n0 + wn * 64;          // multiple of 64 -> exactly one head group
  float bv[4];
#pragma unroll
  for (int j = 0; j < 4; ++j) bv[j] = bias[colbase + j * 16 + lrow];
#pragma unroll
  for (int i = 0; i < 2; ++i)
#pragma unroll
    for (int j = 0; j < 4; ++j)
#pragma unroll
      for (int r = 0; r < 4; ++r) acc[i][j][r] += bv[j];

  int sect = colbase >> 10;            // 0=q, 1=k, 2=v
  if (do_rms && sect < 2) {
    const float* wptr = (sect == 0) ? qn : kn;
    float wv[4];
#pragma unroll
    for (int j = 0; j < 4; ++j) wv[j] = wptr[j * 16 + lrow];
#pragma unroll
    for (int i = 0; i < 2; ++i)
#pragma unroll
      for (int r = 0; r < 4; ++r) {
        float ss = 0.f;
#pragma unroll
        for (int j = 0; j < 4; ++j) { float v = acc[i][j][r]; ss += v * v; }
        ss += __shfl_xor(ss, 1);
        ss += __shfl_xor(ss, 2);
        ss += __shfl_xor(ss, 4);
        ss += __shfl_xor(ss, 8);
        float rstd = rsqrtf(ss * (1.0f / 64.0f) + 1e-6f);
#pragma unroll
        for (int j = 0; j < 4; ++j) acc[i][j][r] *= rstd * wv[j];
      }
  }

#pragma unroll
  for (int i = 0; i < 2; ++i)
#pragma unroll
    for (int j = 0; j < 4; ++j)
#pragma unroll
      for (int r = 0; r < 4; ++r) {
        int row = m0 + wm * 32 + i * 16 + lq * 4 + r;
        int col = colbase + j * 16 + lrow;
        if (out_fp32)
          ((float*)Cout)[(size_t)row * Ncols + col] = acc[i][j][r];
        else
          ((u16*)Cout)[(size_t)row * Ncols + col] = f2bf(acc[i][j][r]);
      }
}

// ---------------- flash attention: 128 q-rows/block, 64-key tiles ---------
// (R4 config restored: single-buffered, 34.8 KB LDS.)
// Fixed-max softmax (RMSNormed q,k -> scaled logits < 8.5; shift-invariant).
// P stored key-permuted (pi(c)=(c&3)*16+(c>>2)) so 4 C-layout values pack
// into one ds_write_b64; V staged pre-permuted to match.
__global__ __launch_bounds__(256)
void flash_attn(u16* __restrict__ qkv, const u16* __restrict__ vt) {
  __shared__ __align__(16) u16 sK[8 * 512];
  __shared__ __align__(16) u16 sV[8 * 512];
  __shared__ __align__(16) u16 sP[128 * 72];
  int tid = threadIdx.x;
  int wave = tid >> 6, lane = tid & 63;
  int lrow = lane & 15, lq = lane >> 4;
  int bh = blockIdx.y, b = bh >> 4, h = bh & 15;
  int q0 = blockIdx.x * 128;
  const float cc = 0.125f * 1.44269504088896340736f;  // scale * log2(e)
  const float co = 8.5f * 1.44269504088896340736f;    // fixed max (logit units)

  bf16x8 qf[2][2];
#pragma unroll
  for (int i = 0; i < 2; ++i)
#pragma unroll
    for (int kq = 0; kq < 2; ++kq)
      qf[i][kq] = *(const bf16x8_ma*)(qkv +
          (size_t)(b * N_ + q0 + wave * 32 + i * 16 + lrow) * N3_ +
          h * D_ + kq * 32 + lq * 8);

  floatx4 aco[2][4];
#pragma unroll
  for (int i = 0; i < 2; ++i)
#pragma unroll
    for (int nd = 0; nd < 4; ++nd) aco[i][nd] = (floatx4){0.f, 0.f, 0.f, 0.f};
  float lsum[2][4];
#pragma unroll
  for (int i = 0; i < 2; ++i)
#pragma unroll
    for (int r = 0; r < 4; ++r) lsum[i][r] = 0.f;

  for (int kt = 0; kt < 32; ++kt) {
    int key0 = kt * 64;
#pragma unroll
    for (int t = 0; t < 2; ++t) {
      int blk = wave * 2 + t;
      int j = blk >> 1, kq = blk & 1;
      const u16* g = qkv + (size_t)(b * N_ + key0 + j * 16 + lrow) * N3_ +
                     C_ + h * D_ + kq * 32 + lq * 8;
      glds16(g, sK + blk * 512);
    }
#pragma unroll
    for (int t = 0; t < 2; ++t) {
      int blk = wave * 2 + t;
      int nd = blk >> 1, kq = blk & 1;
      const u16* g = vt + (size_t)(bh * D_ + nd * 16 + lrow) * N_ +
                     key0 + kq * 32 + lq * 8;
      glds16(g, sV + blk * 512);
    }
    __syncthreads();

    // S = Q K^T (64 keys)
    floatx4 accs[2][4];
#pragma unroll
    for (int j = 0; j < 4; ++j) {
      bf16x8 kf0 = *(const bf16x8_ma*)(sK + (j * 2 + 0) * 512 + lane * 8);
      bf16x8 kf1 = *(const bf16x8_ma*)(sK + (j * 2 + 1) * 512 + lane * 8);
#pragma unroll
      for (int i = 0; i < 2; ++i) {
        floatx4 s = (floatx4){0.f, 0.f, 0.f, 0.f};
        s = __builtin_amdgcn_mfma_f32_16x16x32_bf16(qf[i][0], kf0, s, 0, 0, 0);
        s = __builtin_amdgcn_mfma_f32_16x16x32_bf16(qf[i][1], kf1, s, 0, 0, 0);
        accs[i][j] = s;
      }
    }

    // p = exp2(s*cc - co); pack 4 bf16 -> one ds_write_b64 (keys permuted)
#pragma unroll
    for (int i = 0; i < 2; ++i)
#pragma unroll
      for (int r = 0; r < 4; ++r) {
        float rs = 0.f;
        u32 ub[4];
#pragma unroll
        for (int j = 0; j < 4; ++j) {
          float p = fexp2(fmaf(accs[i][j][r], cc, -co));
          rs += p;
          union { float f; u32 u; } pu; pu.f = p;
          ub[j] = pu.u + 0x8000u;
        }
        lsum[i][r] += rs;
        u32 lo = __builtin_amdgcn_perm(ub[1], ub[0], 0x07060302u);
        u32 hi = __builtin_amdgcn_perm(ub[3], ub[2], 0x07060302u);
        int row = wave * 32 + i * 16 + lq * 4 + r;
        *(u32x2_ma*)(sP + row * 72 + lrow * 4) = (u32x2){lo, hi};
      }

    // O += P V (same-wave write->read; in-order DS per wave)
#pragma unroll
    for (int kq = 0; kq < 2; ++kq) {
      bf16x8 pf0 = *(const bf16x8_ma*)(sP + (wave * 32 + 0 + lrow) * 72 + kq * 32 + lq * 8);
      bf16x8 pf1 = *(const bf16x8_ma*)(sP + (wave * 32 + 16 + lrow) * 72 + kq * 32 + lq * 8);
#pragma unroll
      for (int nd = 0; nd < 4; ++nd) {
        bf16x8 vf = *(const bf16x8_ma*)(sV + (nd * 2 + kq) * 512 + lane * 8);
        aco[0][nd] = __builtin_amdgcn_mfma_f32_16x16x32_bf16(pf0, vf, aco[0][nd], 0, 0, 0);
        aco[1][nd] = __builtin_amdgcn_mfma_f32_16x16x32_bf16(pf1, vf, aco[1][nd], 0, 0, 0);
      }
    }
    __syncthreads();
  }

  // epilogue: reduce l over 16 col-lanes, O/l, store into qkv q-slots
#pragma unroll
  for (int i = 0; i < 2; ++i)
#pragma unroll
    for (int r = 0; r < 4; ++r) {
      float l = lsum[i][r];
      l += __shfl_xor(l, 1);
      l += __shfl_xor(l, 2);
      l += __shfl_xor(l, 4);
      l += __shfl_xor(l, 8);
      float inv = 1.0f / l;
      int row = q0 + wave * 32 + i * 16 + lq * 4 + r;
#pragma unroll
      for (int nd = 0; nd < 4; ++nd)
        qkv[(size_t)(b * N_ + row) * N3_ + h * D_ + nd * 16 + lrow] =
            f2bf(aco[i][nd][r] * inv);
    }
}

extern "C" void kernel_launch(void* const* d_in, const int* in_sizes, int n_in,
                              void* d_out, int out_size, void* d_ws, size_t ws_size,
                              hipStream_t stream) {
  (void)in_sizes; (void)n_in; (void)out_size; (void)ws_size;
  const float* x     = (const float*)d_in[0];
  const float* Wqkv  = (const float*)d_in[1];
  const float* bqkv  = (const float*)d_in[2];
  const float* Wproj = (const float*)d_in[3];
  const float* bproj = (const float*)d_in[4];
  const float* qn    = (const float*)d_in[5];
  const float* kn    = (const float*)d_in[6];
  float* out = (float*)d_out;

  char* ws = (char*)d_ws;
  u16* xb      = (u16*)ws;  ws += (size_t)M_ * C_ * 2;            // 16.8 MB
  u16* Wt_qkv  = (u16*)ws;  ws += (size_t)N3_ * C_ * 2;           // 6.3 MB
  u16* Wt_proj = (u16*)ws;  ws += (size_t)C_ * C_ * 2;            // 2.1 MB
  u16* qkv     = (u16*)ws;  ws += (size_t)M_ * N3_ * 2;           // 50.3 MB
  u16* vt      = (u16*)ws;  ws += (size_t)B_ * H_ * D_ * N_ * 2;  // 16.8 MB

  convert_x<<<dim3(M_ * C_ / 4 / 256), 256, 0, stream>>>(
      (const float4*)x, (uint2*)xb, M_ * C_ / 4);
  transpose_cvt<<<dim3(N3_ / 64, C_ / 64), 256, 0, stream>>>(Wqkv, Wt_qkv, C_, N3_);
  transpose_cvt<<<dim3(C_ / 64, C_ / 64), 256, 0, stream>>>(Wproj, Wt_proj, C_, C_);
  gemm_bt<<<dim3(N3_ / 128, M_ / 64), 256, 0, stream>>>(
      xb, Wt_qkv, bqkv, qkv, N3_, C_, 1, 0, qn, kn);
  transpose_v<<<dim3(N_ / 64, B_ * H_), 256, 0, stream>>>(qkv, vt);
  flash_attn<<<dim3(N_ / 128, B_ * H_), 256, 0, stream>>>(qkv, vt);
  gemm_bt<<<dim3(C_ / 128, M_ / 64), 256, 0, stream>>>(
      qkv, Wt_proj, bproj, out, C_, N3_, 0, 1, qn, kn);
}

// Round 8
// 361.881 us; speedup vs baseline: 1.1841x; 1.1841x over previous
//
#include <hip/hip_runtime.h>
#include <stdint.h>

#define B_ 4
#define N_ 2048
#define C_ 1024
#define H_ 16
#define D_ 64
#define M_ (B_*N_)      // 8192 rows
#define N3_ (3*C_)      // 3072

typedef __attribute__((ext_vector_type(8))) __bf16 bf16x8;
typedef bf16x8 bf16x8_ma __attribute__((may_alias));
typedef __attribute__((ext_vector_type(4))) float floatx4;
typedef unsigned short u16;
typedef unsigned int u32;

typedef __attribute__((address_space(1))) const void void_g;
typedef __attribute__((address_space(3))) void void_l;

__device__ __forceinline__ void glds16(const void* g, void* l) {
  __builtin_amdgcn_global_load_lds((void_g*)g, (void_l*)l, 16, 0, 0);
}

__device__ __forceinline__ u16 f2bf(float f) {
  union { float f; u32 u; } x; x.f = f;
  u32 r = x.u + 0x7fffu + ((x.u >> 16) & 1u);   // RNE
  return (u16)(r >> 16);
}

__device__ __forceinline__ float fexp2(float x) {
#if __has_builtin(__builtin_amdgcn_exp2f)
  return __builtin_amdgcn_exp2f(x);
#else
  return exp2f(x);
#endif
}

// ---------------- x fp32 -> bf16, flat ------------------------------------
__global__ __launch_bounds__(256)
void convert_x(const float4* __restrict__ in, uint2* __restrict__ out, int n4) {
  int idx = blockIdx.x * 256 + threadIdx.x;
  if (idx >= n4) return;
  float4 v = in[idx];
  union { u16 a[4]; uint2 u; } p;
  p.a[0] = f2bf(v.x); p.a[1] = f2bf(v.y); p.a[2] = f2bf(v.z); p.a[3] = f2bf(v.w);
  out[idx] = p.u;
}

// -------- fp32 in[R][Ccols] -> bf16 out[Ccols][R] (transpose+convert) -----
__global__ __launch_bounds__(256)
void transpose_cvt(const float* __restrict__ in, u16* __restrict__ out,
                   int R, int Ccols) {
  __shared__ u16 tile[64][65];
  int c0 = blockIdx.x * 64, r0 = blockIdx.y * 64;
  int tid = threadIdx.x;
#pragma unroll
  for (int it = 0; it < 16; ++it) {
    int idx = it * 256 + tid;
    int r = idx >> 6, c = idx & 63;
    tile[c][r] = f2bf(in[(size_t)(r0 + r) * Ccols + c0 + c]);
  }
  __syncthreads();
#pragma unroll
  for (int it = 0; it < 16; ++it) {
    int idx = it * 256 + tid;
    int oc = idx >> 6, orr = idx & 63;
    out[(size_t)(c0 + oc) * R + r0 + orr] = tile[oc][orr];
  }
}

// -------- V section of qkv(bf16) -> Vt[bh][d][n], key-PERMUTED ------------
// Slot k within each 64-key tile holds actual key m, where
// k = {m5, m3, m2, m4, m1, m0} (bit shuffle). This makes the flash kernel's
// in-lane C-layout -> B-operand P^T repack an identity on key labels.
__global__ __launch_bounds__(256)
void transpose_v(const u16* __restrict__ qkv, u16* __restrict__ vt) {
  __shared__ u16 tile[64][65];
  int bh = blockIdx.y, b = bh >> 4, h = bh & 15;
  int n0 = blockIdx.x * 64;
  int tid = threadIdx.x;
#pragma unroll
  for (int it = 0; it < 16; ++it) {
    int idx = it * 256 + tid;
    int n = idx >> 6, d = idx & 63;
    tile[d][n] = qkv[(size_t)(b * N_ + n0 + n) * N3_ + 2 * C_ + h * D_ + d];
  }
  __syncthreads();
#pragma unroll
  for (int it = 0; it < 16; ++it) {
    int idx = it * 256 + tid;
    int d = idx >> 6, n = idx & 63;          // n = actual key within tile
    int np = (n & 0x23) | ((n & 0x0C) << 1) | ((n & 0x10) >> 2);  // slot
    vt[(size_t)(bh * D_ + d) * N_ + n0 + np] = tile[d][n];
  }
}

// ------- C = A[M,*lda](bf16) * Bt[N,K]^T(bf16) + bias(f32), opt RMSNorm ---
// R3 config: 128x128 tile, 4 waves of 64x64, BK=32 (best measured at K=1024).
__global__ __launch_bounds__(256)
void gemm_bt(const u16* __restrict__ A, const u16* __restrict__ Bt,
             const float* __restrict__ bias, void* __restrict__ Cout,
             int Ncols, int lda, int do_rms, int out_fp32,
             const float* __restrict__ qn, const float* __restrict__ kn) {
  __shared__ __align__(16) u16 sA[8 * 512];
  __shared__ __align__(16) u16 sB[8 * 512];
  const int K = C_;
  int tid = threadIdx.x;
  int wave = tid >> 6, lane = tid & 63;
  int lrow = lane & 15, lq = lane >> 4;
  int n0 = blockIdx.x * 128;
  int m0 = blockIdx.y * 128;
  int wm = wave >> 1, wn = wave & 1;

  floatx4 acc[4][4];
#pragma unroll
  for (int i = 0; i < 4; ++i)
#pragma unroll
    for (int j = 0; j < 4; ++j) acc[i][j] = (floatx4){0.f, 0.f, 0.f, 0.f};

  const u16* ga0 = A  + (size_t)(m0 + (2 * wave + 0) * 16 + lrow) * lda + lq * 8;
  const u16* ga1 = A  + (size_t)(m0 + (2 * wave + 1) * 16 + lrow) * lda + lq * 8;
  const u16* gb0 = Bt + (size_t)(n0 + (2 * wave + 0) * 16 + lrow) * K + lq * 8;
  const u16* gb1 = Bt + (size_t)(n0 + (2 * wave + 1) * 16 + lrow) * K + lq * 8;
  u16* la0 = sA + (2 * wave + 0) * 512;
  u16* la1 = sA + (2 * wave + 1) * 512;
  u16* lb0 = sB + (2 * wave + 0) * 512;
  u16* lb1 = sB + (2 * wave + 1) * 512;

  for (int kt = 0; kt < K; kt += 32) {
    glds16(ga0 + kt, la0);
    glds16(ga1 + kt, la1);
    glds16(gb0 + kt, lb0);
    glds16(gb1 + kt, lb1);
    __syncthreads();
    bf16x8 af[4], bfr[4];
#pragma unroll
    for (int i = 0; i < 4; ++i)
      af[i] = *(const bf16x8_ma*)(sA + (wm * 4 + i) * 512 + lane * 8);
#pragma unroll
    for (int j = 0; j < 4; ++j)
      bfr[j] = *(const bf16x8_ma*)(sB + (wn * 4 + j) * 512 + lane * 8);
#pragma unroll
    for (int i = 0; i < 4; ++i)
#pragma unroll
      for (int j = 0; j < 4; ++j)
        acc[i][j] = __builtin_amdgcn_mfma_f32_16x16x32_bf16(af[i], bfr[j], acc[i][j], 0, 0, 0);
    __syncthreads();
  }

  int colbase = n0 + wn * 64;
  float bv[4];
#pragma unroll
  for (int j = 0; j < 4; ++j) bv[j] = bias[colbase + j * 16 + lrow];
#pragma unroll
  for (int i = 0; i < 4; ++i)
#pragma unroll
    for (int j = 0; j < 4; ++j)
#pragma unroll
      for (int r = 0; r < 4; ++r) acc[i][j][r] += bv[j];

  int sect = colbase >> 10;            // 0=q, 1=k, 2=v
  if (do_rms && sect < 2) {
    const float* wptr = (sect == 0) ? qn : kn;
    float wv[4];
#pragma unroll
    for (int j = 0; j < 4; ++j) wv[j] = wptr[j * 16 + lrow];
#pragma unroll
    for (int i = 0; i < 4; ++i)
#pragma unroll
      for (int r = 0; r < 4; ++r) {
        float ss = 0.f;
#pragma unroll
        for (int j = 0; j < 4; ++j) { float v = acc[i][j][r]; ss += v * v; }
        ss += __shfl_xor(ss, 1);
        ss += __shfl_xor(ss, 2);
        ss += __shfl_xor(ss, 4);
        ss += __shfl_xor(ss, 8);
        float rstd = rsqrtf(ss * (1.0f / 64.0f) + 1e-6f);
#pragma unroll
        for (int j = 0; j < 4; ++j) acc[i][j][r] *= rstd * wv[j];
      }
  }

#pragma unroll
  for (int i = 0; i < 4; ++i)
#pragma unroll
    for (int j = 0; j < 4; ++j)
#pragma unroll
      for (int r = 0; r < 4; ++r) {
        int row = m0 + wm * 64 + i * 16 + lq * 4 + r;
        int col = colbase + j * 16 + lrow;
        if (out_fp32)
          ((float*)Cout)[(size_t)row * Ncols + col] = acc[i][j][r];
        else
          ((u16*)Cout)[(size_t)row * Ncols + col] = f2bf(acc[i][j][r]);
      }
}

// ---------------- flash attention, TRANSPOSED products --------------------
// S^T = K Q^T and O^T = V^T P^T. With the key bit-shuffle baked into vt,
// each lane's S^T C-layout values ARE its P^T B-operand values: P goes
// exp2 -> in-register bf16 pack -> PV MFMA. No P LDS roundtrip, no sP.
// Fixed-max softmax (RMSNormed q,k -> scaled logits < 8.5; shift-invariant).
__global__ __launch_bounds__(256)
void flash_attn(u16* __restrict__ qkv, const u16* __restrict__ vt) {
  __shared__ __align__(16) u16 sK[8 * 512];   // 64 keys x 64 d, (j,kq) blocks
  __shared__ __align__(16) u16 sV[8 * 512];   // 64 d x 64 key-slots, (nd,kq) blocks
  int tid = threadIdx.x;
  int wave = tid >> 6, lane = tid & 63;
  int lrow = lane & 15, lq = lane >> 4;
  int bh = blockIdx.y, b = bh >> 4, h = bh & 15;
  int q0 = blockIdx.x * 128;
  const float cc = 0.125f * 1.44269504088896340736f;  // scale * log2(e)
  const float co = 8.5f * 1.44269504088896340736f;    // fixed max (logit units)

  // Q fragments (used as B-operand: n=lrow=q, k=lq*8=d)
  bf16x8 qf[2][2];
#pragma unroll
  for (int i = 0; i < 2; ++i)
#pragma unroll
    for (int kq = 0; kq < 2; ++kq)
      qf[i][kq] = *(const bf16x8_ma*)(qkv +
          (size_t)(b * N_ + q0 + wave * 32 + i * 16 + lrow) * N3_ +
          h * D_ + kq * 32 + lq * 8);

  floatx4 aco[2][4];   // O^T C-layout: col=lrow=q, row=nd*16+lq*4+r=d
#pragma unroll
  for (int i = 0; i < 2; ++i)
#pragma unroll
    for (int nd = 0; nd < 4; ++nd) aco[i][nd] = (floatx4){0.f, 0.f, 0.f, 0.f};
  float lsum[2] = {0.f, 0.f};   // per-lane: sum of p over this lane's 16 keys

  for (int kt = 0; kt < 32; ++kt) {
    int key0 = kt * 64;
#pragma unroll
    for (int t = 0; t < 2; ++t) {
      int blk = wave * 2 + t;
      int j = blk >> 1, kq = blk & 1;
      const u16* g = qkv + (size_t)(b * N_ + key0 + j * 16 + lrow) * N3_ +
                     C_ + h * D_ + kq * 32 + lq * 8;
      glds16(g, sK + blk * 512);
    }
#pragma unroll
    for (int t = 0; t < 2; ++t) {
      int blk = wave * 2 + t;
      int nd = blk >> 1, kq = blk & 1;
      const u16* g = vt + (size_t)(bh * D_ + nd * 16 + lrow) * N_ +
                     key0 + kq * 32 + lq * 8;
      glds16(g, sV + blk * 512);
    }
    __syncthreads();

    // S^T = K Q^T : accs[i][j] C-layout col=lrow=q, row=j*16+lq*4+r=key
    floatx4 accs[2][4];
#pragma unroll
    for (int j = 0; j < 4; ++j) {
      bf16x8 kf0 = *(const bf16x8_ma*)(sK + (j * 2 + 0) * 512 + lane * 8);
      bf16x8 kf1 = *(const bf16x8_ma*)(sK + (j * 2 + 1) * 512 + lane * 8);
#pragma unroll
      for (int i = 0; i < 2; ++i) {
        floatx4 s = (floatx4){0.f, 0.f, 0.f, 0.f};
        s = __builtin_amdgcn_mfma_f32_16x16x32_bf16(kf0, qf[i][0], s, 0, 0, 0);
        s = __builtin_amdgcn_mfma_f32_16x16x32_bf16(kf1, qf[i][1], s, 0, 0, 0);
        accs[i][j] = s;
      }
    }

    // p = exp2(s*cc - co); pack in-register into P^T B-operand frags:
    // frag[kq].elem[4*(j&1)+r] = p[j=2kq+(j&1)][r]  (key bit-shuffle in vt)
    bf16x8 pf[2][2];
#pragma unroll
    for (int i = 0; i < 2; ++i) {
      union { bf16x8 v; __bf16 e[8]; } pk0, pk1;
      float ls = 0.f;
#pragma unroll
      for (int j = 0; j < 4; ++j)
#pragma unroll
        for (int r = 0; r < 4; ++r) {
          float p = fexp2(fmaf(accs[i][j][r], cc, -co));
          ls += p;
          if (j < 2) pk0.e[(j & 1) * 4 + r] = (__bf16)p;
          else       pk1.e[(j & 1) * 4 + r] = (__bf16)p;
        }
      lsum[i] += ls;
      pf[i][0] = pk0.v;
      pf[i][1] = pk1.v;
    }

    // O^T += V^T P^T
#pragma unroll
    for (int kq = 0; kq < 2; ++kq)
#pragma unroll
      for (int nd = 0; nd < 4; ++nd) {
        bf16x8 vf = *(const bf16x8_ma*)(sV + (nd * 2 + kq) * 512 + lane * 8);
        aco[0][nd] = __builtin_amdgcn_mfma_f32_16x16x32_bf16(vf, pf[0][kq], aco[0][nd], 0, 0, 0);
        aco[1][nd] = __builtin_amdgcn_mfma_f32_16x16x32_bf16(vf, pf[1][kq], aco[1][nd], 0, 0, 0);
      }
    __syncthreads();
  }

  // epilogue: l = sum over the 4 lq-groups sharing this lrow (q-row)
#pragma unroll
  for (int i = 0; i < 2; ++i) {
    float l = lsum[i];
    l += __shfl_xor(l, 16);
    l += __shfl_xor(l, 32);
    float inv = 1.0f / l;
    int row = q0 + wave * 32 + i * 16 + lrow;
#pragma unroll
    for (int nd = 0; nd < 4; ++nd) {
      union { u16 a[4]; uint2 u; } st;
#pragma unroll
      for (int r = 0; r < 4; ++r) st.a[r] = f2bf(aco[i][nd][r] * inv);
      *(uint2*)(qkv + (size_t)(b * N_ + row) * N3_ + h * D_ + nd * 16 + lq * 4) = st.u;
    }
  }
}

extern "C" void kernel_launch(void* const* d_in, const int* in_sizes, int n_in,
                              void* d_out, int out_size, void* d_ws, size_t ws_size,
                              hipStream_t stream) {
  (void)in_sizes; (void)n_in; (void)out_size; (void)ws_size;
  const float* x     = (const float*)d_in[0];
  const float* Wqkv  = (const float*)d_in[1];
  const float* bqkv  = (const float*)d_in[2];
  const float* Wproj = (const float*)d_in[3];
  const float* bproj = (const float*)d_in[4];
  const float* qn    = (const float*)d_in[5];
  const float* kn    = (const float*)d_in[6];
  float* out = (float*)d_out;

  char* ws = (char*)d_ws;
  u16* xb      = (u16*)ws;  ws += (size_t)M_ * C_ * 2;            // 16.8 MB
  u16* Wt_qkv  = (u16*)ws;  ws += (size_t)N3_ * C_ * 2;           // 6.3 MB
  u16* Wt_proj = (u16*)ws;  ws += (size_t)C_ * C_ * 2;            // 2.1 MB
  u16* qkv     = (u16*)ws;  ws += (size_t)M_ * N3_ * 2;           // 50.3 MB
  u16* vt      = (u16*)ws;  ws += (size_t)B_ * H_ * D_ * N_ * 2;  // 16.8 MB

  convert_x<<<dim3(M_ * C_ / 4 / 256), 256, 0, stream>>>(
      (const float4*)x, (uint2*)xb, M_ * C_ / 4);
  transpose_cvt<<<dim3(N3_ / 64, C_ / 64), 256, 0, stream>>>(Wqkv, Wt_qkv, C_, N3_);
  transpose_cvt<<<dim3(C_ / 64, C_ / 64), 256, 0, stream>>>(Wproj, Wt_proj, C_, C_);
  gemm_bt<<<dim3(N3_ / 128, M_ / 128), 256, 0, stream>>>(
      xb, Wt_qkv, bqkv, qkv, N3_, C_, 1, 0, qn, kn);
  transpose_v<<<dim3(N_ / 64, B_ * H_), 256, 0, stream>>>(qkv, vt);
  flash_attn<<<dim3(N_ / 128, B_ * H_), 256, 0, stream>>>(qkv, vt);
  gemm_bt<<<dim3(C_ / 128, M_ / 128), 256, 0, stream>>>(
      qkv, Wt_proj, bproj, out, C_, N3_, 0, 1, qn, kn);
}